// Round 2
// baseline (779.885 us; speedup 1.0000x reference)
//
#include <hip/hip_runtime.h>

#define NSL 8
#define DIN 384
#define DS 128
#define BATCH 32
#define NPOS 4096
#define N_ITERS 3
#define SCALE 0.08838834764831845f
#define EPSV 1e-8f
#define LN_EPS 1e-5f
#define THRESH 0.9f
#define NCH 16          // chunks per batch for deterministic partials (256 rows/chunk)

// ---------------- prep: init slots (in out_raw region) ----------------
__global__ __launch_bounds__(256) void prep_kernel(const float* __restrict__ slot_mu,
                                                   float* __restrict__ slots) {
    int idx = blockIdx.x * 256 + threadIdx.x;
    if (idx < BATCH * NSL * DS) slots[idx] = slot_mu[idx & 127];
}

// ---------------- per-iter: qk[b][s][:] = SCALE * (LN(slots) @ Wq) @ Wk^T ----------------
__global__ __launch_bounds__(128) void qk_kernel(const float* __restrict__ slots,
                                                 const float* __restrict__ gs,
                                                 const float* __restrict__ bs,
                                                 const float* __restrict__ Wq,
                                                 const float* __restrict__ Wk,
                                                 float* __restrict__ qk) {
    __shared__ float s_lds[128];
    __shared__ float q_lds[128];
    __shared__ float red[4];
    int row = blockIdx.x, d = threadIdx.x;
    float x = slots[row * 128 + d];
    float s = x, sq = x * x;
    for (int m = 1; m < 64; m <<= 1) { s += __shfl_xor(s, m, 64); sq += __shfl_xor(sq, m, 64); }
    if ((d & 63) == 0) { red[(d >> 6) * 2] = s; red[(d >> 6) * 2 + 1] = sq; }
    __syncthreads();
    s = red[0] + red[2]; sq = red[1] + red[3];
    float mean = s * (1.f / 128.f), var = sq * (1.f / 128.f) - mean * mean;
    float rstd = rsqrtf(var + LN_EPS);
    s_lds[d] = (x - mean) * rstd * gs[d] + bs[d];
    __syncthreads();
    float acc = 0.f;
    for (int kk = 0; kk < 128; kk++) acc += s_lds[kk] * Wq[kk * 128 + d];
    q_lds[d] = acc;
    __syncthreads();
    for (int i = 0; i < 3; i++) {
        int kk = d + i * 128;
        const float* wkr = Wk + kk * 128;   // Wk is [384][128]; row kk
        float a = 0.f;
        for (int c = 0; c < 128; c++) a += q_lds[c] * wkr[c];
        qk[row * 384 + kk] = a * SCALE;
    }
}

// ---------------- per-iter: fused LN + logits + softmax + attn-out + G/A partials ----------------
__global__ __launch_bounds__(256) void attn_stream_kernel(
    const float* __restrict__ feat,
    const float* __restrict__ g,
    const float* __restrict__ bB,
    const float* __restrict__ qk,
    float* __restrict__ out_attn,
    float* __restrict__ A_part,      // [32][NCH][8]
    float* __restrict__ G_part)      // [32][NCH][8][384]
{
    __shared__ float G_lds[4 * 8 * 384];     // 49152 B
    __shared__ float attn_lds[4][8][64];     // 8192 B
    __shared__ float A_lds[4][8];
    int t = threadIdx.x, w = t >> 6, lane = t & 63;
    int b = blockIdx.y, chunk = blockIdx.x;
    int n0w = chunk * (NPOS / NCH) + w * 64;

    const float2* g2 = (const float2*)g;
    const float2* bb2 = (const float2*)bB;
    float2 gg[3], bb[3];
#pragma unroll
    for (int sg = 0; sg < 3; sg++) { gg[sg] = g2[sg * 64 + lane]; bb[sg] = bb2[sg * 64 + lane]; }
    const float2* qk2 = (const float2*)qk;
    float2 qkr[8][3];
#pragma unroll
    for (int s = 0; s < 8; s++)
#pragma unroll
        for (int sg = 0; sg < 3; sg++)
            qkr[s][sg] = qk2[(b * 8 + s) * 192 + sg * 64 + lane];

    float2 Gacc[8][3];
    float Aacc[8];
#pragma unroll
    for (int s = 0; s < 8; s++) {
        Aacc[s] = 0.f;
#pragma unroll
        for (int sg = 0; sg < 3; sg++) { Gacc[s][sg].x = 0.f; Gacc[s][sg].y = 0.f; }
    }

    const float2* f2p = (const float2*)(feat + (size_t)(b * NPOS + n0w) * DIN);
    for (int j = 0; j < 64; j++) {
        float2 x0 = f2p[(size_t)j * 192 + lane];
        float2 x1 = f2p[(size_t)j * 192 + 64 + lane];
        float2 x2 = f2p[(size_t)j * 192 + 128 + lane];
        float sm = x0.x + x0.y + x1.x + x1.y + x2.x + x2.y;
        float sq = x0.x * x0.x + x0.y * x0.y + x1.x * x1.x + x1.y * x1.y + x2.x * x2.x + x2.y * x2.y;
#pragma unroll
        for (int m = 1; m < 64; m <<= 1) { sm += __shfl_xor(sm, m, 64); sq += __shfl_xor(sq, m, 64); }
        float mean = sm * (1.f / 384.f);
        float var = sq * (1.f / 384.f) - mean * mean;
        float rstd = rsqrtf(var + LN_EPS);
        float2 f0, f1, f2v;
        f0.x = (x0.x - mean) * rstd * gg[0].x + bb[0].x; f0.y = (x0.y - mean) * rstd * gg[0].y + bb[0].y;
        f1.x = (x1.x - mean) * rstd * gg[1].x + bb[1].x; f1.y = (x1.y - mean) * rstd * gg[1].y + bb[1].y;
        f2v.x = (x2.x - mean) * rstd * gg[2].x + bb[2].x; f2v.y = (x2.y - mean) * rstd * gg[2].y + bb[2].y;
        float p[8];
#pragma unroll
        for (int s = 0; s < 8; s++) {
            p[s] = qkr[s][0].x * f0.x + qkr[s][0].y * f0.y
                 + qkr[s][1].x * f1.x + qkr[s][1].y * f1.y
                 + qkr[s][2].x * f2v.x + qkr[s][2].y * f2v.y;
        }
#pragma unroll
        for (int s = 0; s < 8; s++)
#pragma unroll
            for (int m = 1; m < 64; m <<= 1) p[s] += __shfl_xor(p[s], m, 64);
        float mx = p[0];
#pragma unroll
        for (int s = 1; s < 8; s++) mx = fmaxf(mx, p[s]);
        float e[8]; float esum = 0.f;
#pragma unroll
        for (int s = 0; s < 8; s++) { e[s] = __expf(p[s] - mx); esum += e[s]; }
        float inv = 1.f / esum;
        float myv = e[0] * inv;
#pragma unroll
        for (int s = 1; s < 8; s++) { float as = e[s] * inv; myv = (lane == s) ? as : myv; }
        if (lane < 8) attn_lds[w][lane][j] = myv;
#pragma unroll
        for (int s = 0; s < 8; s++) {
            float as = e[s] * inv;
            Aacc[s] += as;
            Gacc[s][0].x += as * f0.x;  Gacc[s][0].y += as * f0.y;
            Gacc[s][1].x += as * f1.x;  Gacc[s][1].y += as * f1.y;
            Gacc[s][2].x += as * f2v.x; Gacc[s][2].y += as * f2v.y;
        }
    }
#pragma unroll
    for (int s = 0; s < 8; s++)
#pragma unroll
        for (int sg = 0; sg < 3; sg++)
            *(float2*)&G_lds[(w * 8 + s) * 384 + sg * 128 + lane * 2] = Gacc[s][sg];
    if (lane == 0) {
#pragma unroll
        for (int s = 0; s < 8; s++) A_lds[w][s] = Aacc[s];
    }
    __syncthreads();
    // deterministic wave-order combine (w0+w1+w2+w3), one partial per block
    for (int q = t; q < 8 * 384; q += 256) {
        float v = ((G_lds[q] + G_lds[3072 + q]) + G_lds[6144 + q]) + G_lds[9216 + q];
        G_part[(size_t)(b * NCH + chunk) * 3072 + q] = v;
    }
    if (t < 8) {
        float v = ((A_lds[0][t] + A_lds[1][t]) + A_lds[2][t]) + A_lds[3][t];
        A_part[(b * NCH + chunk) * 8 + t] = v;
    }
    float* ao = out_attn + (size_t)b * 8 * NPOS + chunk * (NPOS / NCH) + w * 64 + lane;
#pragma unroll
    for (int s = 0; s < 8; s++)
        ao[(size_t)s * NPOS] = attn_lds[w][s][lane];
}

// ---------------- per-iter: reduce partials + @Wv + GRU + LN + MLP -> slots ----------------
__global__ __launch_bounds__(128) void gru_kernel(
    const float* __restrict__ G_part,
    const float* __restrict__ A_part,
    const float* __restrict__ Wv,
    const float* __restrict__ W_ih, const float* __restrict__ W_hh,
    const float* __restrict__ b_ih, const float* __restrict__ b_hh,
    const float* __restrict__ gm, const float* __restrict__ bm,
    const float* __restrict__ W1, const float* __restrict__ b1v,
    const float* __restrict__ W2, const float* __restrict__ b2v,
    float* __restrict__ slots)
{
    __shared__ float G_l[384], u_l[128], h_l[128], m_l[128], hid_l[256];
    __shared__ float red[4];
    int row = blockIdx.x, d = threadIdx.x;
    int b = row >> 3, sl = row & 7;
    float asum = 0.f;
    for (int ch = 0; ch < NCH; ch++) asum += A_part[(b * NCH + ch) * 8 + sl];
    float inv = 1.f / (asum + EPSV);
    for (int i = 0; i < 3; i++) {
        int kk = d + i * 128;
        float gsum = 0.f;
        for (int ch = 0; ch < NCH; ch++)
            gsum += G_part[(size_t)((b * NCH + ch) * 8 + sl) * 384 + kk];
        G_l[kk] = gsum;
    }
    __syncthreads();
    float u = 0.f;
    for (int kk = 0; kk < 384; kk++) u += G_l[kk] * Wv[kk * 128 + d];
    u *= inv;
    float h = slots[row * 128 + d];
    u_l[d] = u; h_l[d] = h;
    __syncthreads();
    float gx[3], gh[3];
    for (int jg = 0; jg < 3; jg++) {
        int j = jg * 128 + d;
        const float* wi = W_ih + j * 128;
        const float* wh = W_hh + j * 128;
        float ax = b_ih[j], ah = b_hh[j];
        for (int kk = 0; kk < 128; kk++) { ax += u_l[kk] * wi[kk]; ah += h_l[kk] * wh[kk]; }
        gx[jg] = ax; gh[jg] = ah;
    }
    float r = 1.f / (1.f + expf(-(gx[0] + gh[0])));
    float z = 1.f / (1.f + expf(-(gx[1] + gh[1])));
    float nn = tanhf(gx[2] + r * gh[2]);
    float hn = (1.f - z) * nn + z * h;
    float s = hn, sq = hn * hn;
    for (int m = 1; m < 64; m <<= 1) { s += __shfl_xor(s, m, 64); sq += __shfl_xor(sq, m, 64); }
    if ((d & 63) == 0) { red[(d >> 6) * 2] = s; red[(d >> 6) * 2 + 1] = sq; }
    __syncthreads();
    s = red[0] + red[2]; sq = red[1] + red[3];
    float mean = s * (1.f / 128.f), var = sq * (1.f / 128.f) - mean * mean;
    float rstd = rsqrtf(var + LN_EPS);
    m_l[d] = (hn - mean) * rstd * gm[d] + bm[d];
    __syncthreads();
    for (int jj = 0; jj < 2; jj++) {
        int j = jj * 128 + d;
        float a = b1v[j];
        for (int kk = 0; kk < 128; kk++) a += m_l[kk] * W1[kk * 256 + j];
        hid_l[j] = a / (1.f + expf(-a));   // silu
    }
    __syncthreads();
    float o = hn + b2v[d];
    for (int kk = 0; kk < 256; kk++) o += hid_l[kk] * W2[kk * 128 + d];
    slots[row * 128 + d] = o;
}

// ---------------- merge map (first-index argmax tie-break) + merged ----------------
__global__ __launch_bounds__(128) void merge_kernel(const float* __restrict__ slots,
                                                    float* __restrict__ out_merged,
                                                    float* __restrict__ out_mm) {
    __shared__ float slb[8][128];
    __shared__ float nrm[8];
    __shared__ float simb[64];
    __shared__ int mm[8];
    int b = blockIdx.x, t = threadIdx.x;
    for (int s8 = 0; s8 < 8; s8++) slb[s8][t] = slots[(b * 8 + s8) * 128 + t];
    __syncthreads();
    if (t < 8) {
        float ss = 0.f;
        for (int kk = 0; kk < 128; kk++) ss += slb[t][kk] * slb[t][kk];
        nrm[t] = fmaxf(sqrtf(ss), 1e-12f);
    }
    __syncthreads();
    if (t < 64) {
        int i = t >> 3, j = t & 7;
        float dot = 0.f;
        for (int kk = 0; kk < 128; kk++) dot += slb[i][kk] * slb[j][kk];
        simb[t] = dot / (nrm[i] * nrm[j]) - ((i == j) ? 2.f : 0.f);
    }
    __syncthreads();
    if (t < 64) {
        float v = simb[t];
        int myi = t >> 3, myj = t & 7;
        int mt = t;   // lanes 0..7 track merge_target
        for (int it = 0; it < 8; it++) {
            float bv = v; int bi = t;
            for (int m = 1; m < 64; m <<= 1) {
                float ov = __shfl_xor(bv, m, 64);
                int oi = __shfl_xor(bi, m, 64);
                if (ov > bv || (ov == bv && oi < bi)) { bv = ov; bi = oi; }
            }
            int rr = bi >> 3, cc = bi & 7;
            if (bv > THRESH) {
                int src = rr > cc ? rr : cc;
                int tgt = rr < cc ? rr : cc;
                if (t == src) mt = tgt;
                if (myi == src || myj == src) v = -2.f;
            }
        }
        if (t < 8) mm[t] = mt;
    }
    __syncthreads();
    for (int tt = 0; tt < 8; tt++) {
        float ssum = 0.f; int cnt = 0;
        for (int s8 = 0; s8 < 8; s8++) {
            if (mm[s8] == tt) { ssum += slb[s8][t]; cnt++; }
        }
        out_merged[(b * 8 + tt) * 128 + t] = ssum / fmaxf((float)cnt, 1.f);
    }
    if (t < 8) out_mm[b * 8 + t] = (float)mm[t];
}

extern "C" void kernel_launch(void* const* d_in, const int* in_sizes, int n_in,
                              void* d_out, int out_size, void* d_ws, size_t ws_size,
                              hipStream_t stream) {
    const float* feat    = (const float*)d_in[0];
    const float* ln_in_g = (const float*)d_in[1];
    const float* ln_in_b = (const float*)d_in[2];
    const float* Wk      = (const float*)d_in[3];
    const float* Wv      = (const float*)d_in[4];
    const float* Wq      = (const float*)d_in[5];
    const float* ln_s_g  = (const float*)d_in[6];
    const float* ln_s_b  = (const float*)d_in[7];
    const float* W_ih    = (const float*)d_in[8];
    const float* W_hh    = (const float*)d_in[9];
    const float* b_ih    = (const float*)d_in[10];
    const float* b_hh    = (const float*)d_in[11];
    const float* ln_m_g  = (const float*)d_in[12];
    const float* ln_m_b  = (const float*)d_in[13];
    const float* W1      = (const float*)d_in[14];
    const float* b1      = (const float*)d_in[15];
    const float* W2      = (const float*)d_in[16];
    const float* b2      = (const float*)d_in[17];
    const float* slot_mu = (const float*)d_in[18];

    float* out        = (float*)d_out;
    float* out_merged = out;                       // 32768
    float* out_attn   = out + 32768;               // 1048576
    float* out_mm     = out + 32768 + 1048576;     // 256
    float* out_raw    = out_mm + 256;              // 32768 — slots working buffer

    // workspace: 6,701,056 B total
    float* qk     = (float*)d_ws;                  // [256][384]       = 393,216 B
    float* A_part = qk + 98304;                    // [32][16][8]      =  16,384 B
    float* G_part = A_part + 4096;                 // [32][16][8][384] = 6,291,456 B

    prep_kernel<<<128, 256, 0, stream>>>(slot_mu, out_raw);
    for (int it = 0; it < N_ITERS; it++) {
        qk_kernel<<<256, 128, 0, stream>>>(out_raw, ln_s_g, ln_s_b, Wq, Wk, qk);
        attn_stream_kernel<<<dim3(NCH, BATCH), 256, 0, stream>>>(feat, ln_in_g, ln_in_b, qk,
                                                                 out_attn, A_part, G_part);
        gru_kernel<<<256, 128, 0, stream>>>(G_part, A_part, Wv, W_ih, W_hh, b_ih, b_hh,
                                            ln_m_g, ln_m_b, W1, b1, W2, b2, out_raw);
    }
    merge_kernel<<<32, 128, 0, stream>>>(out_raw, out_merged, out_mm);
}

// Round 3
// 413.951 us; speedup vs baseline: 1.8840x; 1.8840x over previous
//
#include <hip/hip_runtime.h>

#define NSL 8
#define DIN 384
#define DS 128
#define BATCH 32
#define NPOS 4096
#define LN_EPS 1e-5f
#define THRESH 0.9f
#define NCH 64          // feature chunks per batch (64 rows each)

// attn_norm constant: attn = 0.125 exactly (identical slots); sum = 512.0 exactly;
// 512.0f + 1e-8f == 512.0f; 0.125/512 = 2^-12 (exact power of two)
#define ATTN_NORM_C 0.000244140625f

// ---------------- P0: transpose W_ih / W_hh for coalesced column access ----------------
__global__ __launch_bounds__(256) void prep_kernel(const float* __restrict__ Wih,
                                                   const float* __restrict__ Whh,
                                                   float* __restrict__ WihT,
                                                   float* __restrict__ WhhT) {
    int idx = blockIdx.x * 256 + threadIdx.x;   // 384*128 = 49152
    if (idx < 49152) {
        int j = idx / 128, k = idx % 128;
        WihT[k * 384 + j] = Wih[idx];
        WhhT[k * 384 + j] = Whh[idx];
    }
}

// ---------------- K1: streaming column-sum of LN(features) + attn=0.125 fill ----------------
__global__ __launch_bounds__(256) void colsum_kernel(const float* __restrict__ feat,
                                                     const float* __restrict__ g,
                                                     const float* __restrict__ bB,
                                                     float* __restrict__ G_part,   // [32][NCH][384]
                                                     float* __restrict__ out_attn) {
    __shared__ float S_lds[4][384];
    int t = threadIdx.x, w = t >> 6, lane = t & 63;
    int b = blockIdx.y, ch = blockIdx.x;
    int n0 = ch * 64 + w * 16;

    const float2* g2 = (const float2*)g;
    const float2* b2p = (const float2*)bB;
    float2 gg0 = g2[lane], gg1 = g2[64 + lane], gg2 = g2[128 + lane];
    float2 bb0 = b2p[lane], bb1 = b2p[64 + lane], bb2 = b2p[128 + lane];

    float2 a0 = {0.f, 0.f}, a1 = {0.f, 0.f}, a2 = {0.f, 0.f};
    const float2* fp = (const float2*)(feat + ((size_t)b * NPOS + n0) * DIN);
    for (int j = 0; j < 16; j++) {
        float2 x0 = fp[(size_t)j * 192 + lane];
        float2 x1 = fp[(size_t)j * 192 + 64 + lane];
        float2 x2 = fp[(size_t)j * 192 + 128 + lane];
        float sm = x0.x + x0.y + x1.x + x1.y + x2.x + x2.y;
        float sq = x0.x * x0.x + x0.y * x0.y + x1.x * x1.x + x1.y * x1.y
                 + x2.x * x2.x + x2.y * x2.y;
#pragma unroll
        for (int m = 1; m < 64; m <<= 1) { sm += __shfl_xor(sm, m, 64); sq += __shfl_xor(sq, m, 64); }
        float mean = sm * (1.f / 384.f);
        float var = sq * (1.f / 384.f) - mean * mean;
        float rstd = rsqrtf(var + LN_EPS);
        a0.x += (x0.x - mean) * rstd * gg0.x + bb0.x;
        a0.y += (x0.y - mean) * rstd * gg0.y + bb0.y;
        a1.x += (x1.x - mean) * rstd * gg1.x + bb1.x;
        a1.y += (x1.y - mean) * rstd * gg1.y + bb1.y;
        a2.x += (x2.x - mean) * rstd * gg2.x + bb2.x;
        a2.y += (x2.y - mean) * rstd * gg2.y + bb2.y;
    }
    *(float2*)&S_lds[w][lane * 2] = a0;
    *(float2*)&S_lds[w][128 + lane * 2] = a1;
    *(float2*)&S_lds[w][256 + lane * 2] = a2;
    __syncthreads();
    // deterministic wave-order combine
    for (int q = t; q < 384; q += 256) {
        float v = ((S_lds[0][q] + S_lds[1][q]) + S_lds[2][q]) + S_lds[3][q];
        G_part[((size_t)b * NCH + ch) * 384 + q] = v;
    }
    // attn output is exactly 0.125 everywhere (softmax of identical logits)
    int s = t >> 5, p = t & 31;
    size_t ao = ((size_t)(b * 8 + s)) * NPOS + ch * 64;
    out_attn[ao + p] = 0.125f;
    out_attn[ao + 32 + p] = 0.125f;
}

// ---------------- K2: reduce partials -> u; 3x (GRU + LN + MLP); merge outputs ----------------
__global__ __launch_bounds__(128) void slots_kernel(
    const float* __restrict__ G_part,
    const float* __restrict__ Wv,
    const float* __restrict__ slot_mu,
    const float* __restrict__ WihT, const float* __restrict__ WhhT,
    const float* __restrict__ b_ih, const float* __restrict__ b_hh,
    const float* __restrict__ gm, const float* __restrict__ bm,
    const float* __restrict__ W1, const float* __restrict__ b1v,
    const float* __restrict__ W2, const float* __restrict__ b2v,
    float* __restrict__ out_merged, float* __restrict__ out_mm,
    float* __restrict__ out_raw)
{
    __shared__ float S_l[384], u_l[128], h_l[128], m_l[128], hid_l[256];
    __shared__ float red[4];
    int b = blockIdx.x, d = threadIdx.x;

    // reduce column-sum partials (fixed chunk order -> deterministic)
    for (int i = 0; i < 3; i++) {
        int q = d + i * 128;
        float s = 0.f;
        for (int ch = 0; ch < NCH; ch++) s += G_part[((size_t)b * NCH + ch) * 384 + q];
        S_l[q] = s;
    }
    __syncthreads();
    // u = attn_norm * (sum_f_ln @ Wv)
    float u = 0.f;
    for (int k = 0; k < 384; k++) u += S_l[k] * Wv[k * 128 + d];
    u *= ATTN_NORM_C;
    u_l[d] = u;
    float h = slot_mu[d];
    h_l[d] = h;
    __syncthreads();

    // gx = W_ih @ u + b_ih : constant across iterations (u is iteration-invariant)
    float gx[3];
#pragma unroll
    for (int jg = 0; jg < 3; jg++) {
        int j = jg * 128 + d;
        float ax = b_ih[j];
        for (int k = 0; k < 128; k++) ax += u_l[k] * WihT[k * 384 + j];
        gx[jg] = ax;
    }

    for (int it = 0; it < 3; it++) {
        float gh[3];
#pragma unroll
        for (int jg = 0; jg < 3; jg++) {
            int j = jg * 128 + d;
            float ah = b_hh[j];
            for (int k = 0; k < 128; k++) ah += h_l[k] * WhhT[k * 384 + j];
            gh[jg] = ah;
        }
        float r = 1.f / (1.f + expf(-(gx[0] + gh[0])));
        float z = 1.f / (1.f + expf(-(gx[1] + gh[1])));
        float nn = tanhf(gx[2] + r * gh[2]);
        float hn = (1.f - z) * nn + z * h;
        // LN(hn)
        float s = hn, sq = hn * hn;
#pragma unroll
        for (int m = 1; m < 64; m <<= 1) { s += __shfl_xor(s, m, 64); sq += __shfl_xor(sq, m, 64); }
        if ((d & 63) == 0) { red[(d >> 6) * 2] = s; red[(d >> 6) * 2 + 1] = sq; }
        __syncthreads();
        s = red[0] + red[2]; sq = red[1] + red[3];
        float mean = s * (1.f / 128.f), var = sq * (1.f / 128.f) - mean * mean;
        float rstd = rsqrtf(var + LN_EPS);
        m_l[d] = (hn - mean) * rstd * gm[d] + bm[d];
        __syncthreads();
        // MLP
#pragma unroll
        for (int jj = 0; jj < 2; jj++) {
            int j = jj * 128 + d;
            float a = b1v[j];
            for (int k = 0; k < 128; k++) a += m_l[k] * W1[k * 256 + j];
            hid_l[j] = a / (1.f + expf(-a));   // silu
        }
        __syncthreads();
        float o = hn + b2v[d];
        for (int k = 0; k < 256; k++) o += hid_l[k] * W2[k * 128 + d];
        h = o;
        __syncthreads();
        h_l[d] = h;
        __syncthreads();
    }

    // merge: all 8 slots are identical copies of h; sim(off-diag) = cos(h,h)
    float s2 = h * h;
#pragma unroll
    for (int m = 1; m < 64; m <<= 1) s2 += __shfl_xor(s2, m, 64);
    if ((d & 63) == 0) red[d >> 6] = s2;
    __syncthreads();
    float ss = red[0] + red[1];
    float nrm = fmaxf(sqrtf(ss), 1e-12f);
    float simv = ss / (nrm * nrm);
    int allmerge = (simv > THRESH) ? 1 : 0;   // true unless h degenerate

#pragma unroll
    for (int sl = 0; sl < 8; sl++) {
        out_raw[((size_t)(b * 8 + sl)) * 128 + d] = h;
        float mv = (sl == 0) ? h : (allmerge ? 0.f : h);
        out_merged[((size_t)(b * 8 + sl)) * 128 + d] = mv;
    }
    if (d < 8) out_mm[b * 8 + d] = allmerge ? 0.f : (float)d;
}

extern "C" void kernel_launch(void* const* d_in, const int* in_sizes, int n_in,
                              void* d_out, int out_size, void* d_ws, size_t ws_size,
                              hipStream_t stream) {
    const float* feat    = (const float*)d_in[0];
    const float* ln_in_g = (const float*)d_in[1];
    const float* ln_in_b = (const float*)d_in[2];
    const float* Wv      = (const float*)d_in[4];
    const float* W_ih    = (const float*)d_in[8];
    const float* W_hh    = (const float*)d_in[9];
    const float* b_ih    = (const float*)d_in[10];
    const float* b_hh    = (const float*)d_in[11];
    const float* ln_m_g  = (const float*)d_in[12];
    const float* ln_m_b  = (const float*)d_in[13];
    const float* W1      = (const float*)d_in[14];
    const float* b1      = (const float*)d_in[15];
    const float* W2      = (const float*)d_in[16];
    const float* b2      = (const float*)d_in[17];
    const float* slot_mu = (const float*)d_in[18];

    float* out        = (float*)d_out;
    float* out_merged = out;                       // 32768
    float* out_attn   = out + 32768;               // 1048576
    float* out_mm     = out + 32768 + 1048576;     // 256
    float* out_raw    = out_mm + 256;              // 32768

    // workspace: 3,538,944 B (round-2's 6.7 MB was proven safe)
    float* G_part = (float*)d_ws;                  // [32][NCH][384] = 3,145,728 B
    float* WihT   = G_part + 32 * NCH * 384;       // 196,608 B
    float* WhhT   = WihT + 49152;                  // 196,608 B

    prep_kernel<<<192, 256, 0, stream>>>(W_ih, W_hh, WihT, WhhT);
    colsum_kernel<<<dim3(NCH, BATCH), 256, 0, stream>>>(feat, ln_in_g, ln_in_b,
                                                        G_part, out_attn);
    slots_kernel<<<32, 128, 0, stream>>>(G_part, Wv, slot_mu, WihT, WhhT,
                                         b_ih, b_hh, ln_m_g, ln_m_b,
                                         W1, b1, W2, b2,
                                         out_merged, out_mm, out_raw);
}